// Round 6
// baseline (1646.104 us; speedup 1.0000x reference)
//
#include <hip/hip_runtime.h>
#include <math.h>

// ---------------------------------------------------------------------------
// GAT x3 + BN on MI355X.
//   setup:  hist(dst) -> 3-phase parallel scan -> counting-sort edges (CSR).
//   layer:  P = We@a_edge + self logit
//           k_gemm2: h = BN(X)@W (W in LDS, 4x4 reg tile), writes h as BF16,
//                    fused al_s/al_d/es epilogue
//           k_alpha3: meta[e] = {src, p=exp(lrelu(als+ald+ale))}  (8 B packed)
//           k_agg6: one wave per node; 16 lanes per edge (uint4 = 8 bf16
//                   features/lane), 4 edges per gather instruction, 8-deep
//                   burst = 32 edges / 128 cache lines in flight per wave.
//                   Meta read via direct coalesced loads (no shuffles in the
//                   address path).  Groups combined per NODE via shfl_xor.
//           k_bnfinal -> scale/shift consumed by NEXT layer's gemm staging;
//           k_bnapply only for the final output.
// R6: R5 (half-wave shfl broadcast) regressed 125->220us: bpermute in the
// address chain + VGPR 40.  Gather-MLP is the limiter -> 4 rows/instr,
// shuffle-free hot loop.
// ---------------------------------------------------------------------------

struct __align__(16) Edge { int src; float e0, e1, e2; };

__device__ __forceinline__ unsigned short f2bf(float x) {
  unsigned u = __float_as_uint(x);
  unsigned r = (u + 0x7FFFu + ((u >> 16) & 1u)) >> 16;  // RNE
  return (unsigned short)r;
}
__device__ __forceinline__ float bf_lo(unsigned u) { return __uint_as_float(u << 16); }
__device__ __forceinline__ float bf_hi(unsigned u) { return __uint_as_float(u & 0xFFFF0000u); }

__global__ void k_hist(const int* __restrict__ dst, int E, int* __restrict__ deg) {
  int i = blockIdx.x * blockDim.x + threadIdx.x;
  if (i < E) atomicAdd(&deg[dst[i]], 1);
}

__global__ void k_ea_sum(const float* __restrict__ ea, int E, float* __restrict__ ea_sum) {
  float s0 = 0.f, s1 = 0.f, s2 = 0.f;
  for (int i = blockIdx.x * blockDim.x + threadIdx.x; i < E; i += gridDim.x * blockDim.x) {
    s0 += ea[i * 3 + 0]; s1 += ea[i * 3 + 1]; s2 += ea[i * 3 + 2];
  }
  for (int off = 32; off; off >>= 1) {
    s0 += __shfl_down(s0, off); s1 += __shfl_down(s1, off); s2 += __shfl_down(s2, off);
  }
  __shared__ float ls[3][4];
  int lane = threadIdx.x & 63, w = threadIdx.x >> 6;
  if (lane == 0) { ls[0][w] = s0; ls[1][w] = s1; ls[2][w] = s2; }
  __syncthreads();
  if (threadIdx.x == 0) {
    float t0 = 0.f, t1 = 0.f, t2 = 0.f;
    for (int ww = 0; ww < 4; ++ww) { t0 += ls[0][ww]; t1 += ls[1][ww]; t2 += ls[2][ww]; }
    atomicAdd(&ea_sum[0], t0); atomicAdd(&ea_sum[1], t1); atomicAdd(&ea_sum[2], t2);
  }
}

__device__ __forceinline__ int wave_incl_scan(int x, int lane) {
  for (int off = 1; off < 64; off <<= 1) {
    int t = __shfl_up(x, off);
    if (lane >= off) x += t;
  }
  return x;
}

__global__ __launch_bounds__(1024) void k_scan_a(const int* __restrict__ deg, int n,
                                                 int* __restrict__ start,
                                                 int* __restrict__ bsum) {
  __shared__ int wsum[16];
  int t = threadIdx.x, lane = t & 63, w = t >> 6;
  int i = blockIdx.x * 1024 + t;
  int v = (i < n) ? deg[i] : 0;
  int x = wave_incl_scan(v, lane);
  if (lane == 63) wsum[w] = x;
  __syncthreads();
  if (w == 0 && lane < 16) {
    int s = wsum[lane];
    for (int off = 1; off < 16; off <<= 1) {
      int u = __shfl_up(s, off);
      if (lane >= off) s += u;
    }
    wsum[lane] = s;
  }
  __syncthreads();
  int woff = w ? wsum[w - 1] : 0;
  if (i < n) start[i] = x - v + woff;
  if (t == 1023) bsum[blockIdx.x] = wsum[15];
}

__global__ void k_scan_b(int* __restrict__ bsum, int nb, int* __restrict__ start, int n) {
  int lane = threadIdx.x;  // 64
  int v = (lane < nb) ? bsum[lane] : 0;
  int x = wave_incl_scan(v, lane);
  if (lane < nb) bsum[lane] = x - v;
  if (lane == nb - 1) start[n] = x;
}

__global__ void k_scan_c(int* __restrict__ start, const int* __restrict__ bsum, int n,
                         int* __restrict__ cursor) {
  int i = blockIdx.x * blockDim.x + threadIdx.x;
  if (i < n) {
    int s = start[i] + bsum[i >> 10];
    start[i] = s;
    cursor[i] = s;
  }
}

__global__ void k_scatter(const int* __restrict__ src, const int* __restrict__ dst,
                          const float* __restrict__ ea, int E,
                          int* __restrict__ cursor, Edge* __restrict__ edges,
                          int* __restrict__ dsts) {
  int i = blockIdx.x * blockDim.x + threadIdx.x;
  if (i >= E) return;
  int d = dst[i];
  int pos = atomicAdd(&cursor[d], 1);
  Edge e;
  e.src = src[i];
  e.e0 = ea[i * 3 + 0]; e.e1 = ea[i * 3 + 1]; e.e2 = ea[i * 3 + 2];
  edges[pos] = e;
  dsts[pos] = d;
}

__global__ void k_initid(float* __restrict__ sc, float* __restrict__ sh) {
  int c = threadIdx.x;  // 128
  sc[c] = 1.f; sh[c] = 0.f;
}

__global__ void k_param(const float* __restrict__ We, const float* __restrict__ ae,
                        const float* __restrict__ ea_sum, float invE, float* __restrict__ P) {
  int lane = threadIdx.x;  // 64
  float a0 = ae[lane], a1 = ae[64 + lane];
  float p0 = We[0 * 128 + lane] * a0 + We[0 * 128 + 64 + lane] * a1;
  float p1 = We[1 * 128 + lane] * a0 + We[1 * 128 + 64 + lane] * a1;
  float p2 = We[2 * 128 + lane] * a0 + We[2 * 128 + 64 + lane] * a1;
  for (int off = 32; off; off >>= 1) {
    p0 += __shfl_down(p0, off); p1 += __shfl_down(p1, off); p2 += __shfl_down(p2, off);
  }
  if (lane == 0) {
    P[0] = p0; P[1] = p1; P[2] = p2;
    P[3] = ea_sum[0] * invE * p0 + ea_sum[1] * invE * p1 + ea_sum[2] * invE * p2;
  }
}

// h[N,128] = (X*bnsc+bnsh) @ W, stored as bf16 rows (256 B).  W in LDS,
// 32-row tiles, 4 rows x 4 cols per thread.  Fused al_s/al_d/es epilogue.
__global__ __launch_bounds__(256) void k_gemm2(
    const float* __restrict__ X, const float* __restrict__ Wm,
    const float* __restrict__ bnsc, const float* __restrict__ bnsh,
    const float* __restrict__ as, const float* __restrict__ ad,
    const float* __restrict__ P,
    unsigned* __restrict__ hb, float* __restrict__ al_s, float* __restrict__ al_d,
    float* __restrict__ es, int n) {
  __shared__ float wl[128 * 128];
  __shared__ float xs[32 * 128];
  int t = threadIdx.x;
  for (int i = t; i < 4096; i += 256) ((float4*)wl)[i] = ((const float4*)Wm)[i];
  int c32 = t & 31;
  int c4 = c32 << 2;
  int rq = t >> 5;
  int lane = t & 63;
  float4 av_s = *(const float4*)(as + c4);
  float4 av_d = *(const float4*)(ad + c4);
  float cself = P[3];
  int ntiles = (n + 31) >> 5;
  for (int tile = blockIdx.x; tile < ntiles; tile += gridDim.x) {
    int r0 = tile << 5;
    __syncthreads();
    for (int i = t; i < 1024; i += 256) {
      int rr = i >> 5, cc = i & 31;
      int g = r0 + rr;
      float4 v;
      if (g < n) {
        v = ((const float4*)(X + (size_t)g * 128))[cc];
        float4 sc = ((const float4*)bnsc)[cc];
        float4 sh = ((const float4*)bnsh)[cc];
        v.x = fmaf(v.x, sc.x, sh.x); v.y = fmaf(v.y, sc.y, sh.y);
        v.z = fmaf(v.z, sc.z, sh.z); v.w = fmaf(v.w, sc.w, sh.w);
      } else { v.x = v.y = v.z = v.w = 0.f; }
      ((float4*)xs)[i] = v;
    }
    __syncthreads();
    float4 acc[4];
    for (int r = 0; r < 4; ++r) { acc[r].x = acc[r].y = acc[r].z = acc[r].w = 0.f; }
    const float* xr = xs + (rq << 2) * 128;
#pragma unroll 4
    for (int k = 0; k < 128; ++k) {
      float4 w4 = ((const float4*)wl)[(k << 5) + c32];
#pragma unroll
      for (int r = 0; r < 4; ++r) {
        float xv = xr[r * 128 + k];
        acc[r].x = fmaf(xv, w4.x, acc[r].x);
        acc[r].y = fmaf(xv, w4.y, acc[r].y);
        acc[r].z = fmaf(xv, w4.z, acc[r].z);
        acc[r].w = fmaf(xv, w4.w, acc[r].w);
      }
    }
    int gbase = r0 + (rq << 2);
#pragma unroll
    for (int r = 0; r < 4; ++r) {
      int g = gbase + r;
      float4 o = acc[r];
      if (g < n) {
        unsigned u01 = ((unsigned)f2bf(o.y) << 16) | (unsigned)f2bf(o.x);
        unsigned u23 = ((unsigned)f2bf(o.w) << 16) | (unsigned)f2bf(o.z);
        uint2 uu = {u01, u23};
        *(uint2*)(hb + (size_t)g * 64 + (c32 << 1)) = uu;
      }
      float ps = o.x * av_s.x + o.y * av_s.y + o.z * av_s.z + o.w * av_s.w;
      float pd = o.x * av_d.x + o.y * av_d.y + o.z * av_d.z + o.w * av_d.w;
      for (int off = 16; off; off >>= 1) {
        ps += __shfl_xor(ps, off);
        pd += __shfl_xor(pd, off);
      }
      if ((lane & 31) == 0 && g < n) {
        al_s[g] = ps; al_d[g] = pd;
        float a = ps + pd + cself;
        a = a > 0.f ? a : 0.2f * a;
        es[g] = __expf(a);
      }
    }
  }
}

// meta[e] = {src, p=exp(lrelu_0.2(al_s[src]+al_d[dst]+ea.We@ae))}
__global__ __launch_bounds__(256) void k_alpha3(const float4* __restrict__ edges,
                                                const int* __restrict__ dsts,
                                                const float* __restrict__ al_s,
                                                const float* __restrict__ al_d,
                                                const float* __restrict__ P,
                                                uint2* __restrict__ meta, int E) {
  int i = blockIdx.x * blockDim.x + threadIdx.x;
  if (i >= E) return;
  float4 ef = edges[i];
  int s = __float_as_int(ef.x);
  float a = al_s[s] + al_d[dsts[i]] + ef.y * P[0] + ef.z * P[1] + ef.w * P[2];
  a = a > 0.f ? a : 0.2f * a;
  uint2 m = {(unsigned)s, __float_as_uint(__expf(a))};
  meta[i] = m;
}

// one wave per node.  16 lanes per edge: lane = 16*g + q gathers uint4
// (features 8q..8q+7) of edge-group g; one gather instruction covers 4 rows
// (16 cache lines).  Meta via direct coalesced loads meta[eb+4k+g] (1 line,
// no shuffles).  8-deep burst = 32 edges / 128 lines in flight.  Tail edges
// clamped to e1-1 with p=0.  Groups combined per node via shfl_xor(16,32).
__global__ __launch_bounds__(256, 4) void k_agg6(const uint2* __restrict__ meta,
                                                 const int* __restrict__ start,
                                                 const uint4* __restrict__ hb4,
                                                 const float* __restrict__ es,
                                                 const float* __restrict__ bias,
                                                 float* __restrict__ y,
                                                 float* __restrict__ colsum,
                                                 float* __restrict__ colsumsq, int n) {
  int lane = threadIdx.x & 63;
  int w = threadIdx.x >> 6;
  int g = lane >> 4;   // edge slot within the 4-edge instruction group
  int q = lane & 15;   // feature segment: features 8q..8q+7
  int gw = (blockIdx.x * blockDim.x + threadIdx.x) >> 6;
  int nw = (gridDim.x * blockDim.x) >> 6;
  float4 bA = ((const float4*)bias)[q << 1];
  float4 bB = ((const float4*)bias)[(q << 1) + 1];
  float sS[8] = {0.f, 0.f, 0.f, 0.f, 0.f, 0.f, 0.f, 0.f};
  float sQ[8] = {0.f, 0.f, 0.f, 0.f, 0.f, 0.f, 0.f, 0.f};
  for (int i = gw; i < n; i += nw) {
    int e0 = __builtin_amdgcn_readfirstlane(start[i]);
    int e1 = __builtin_amdgcn_readfirstlane(start[i + 1]);
    float eself = es[i];
    uint4 sv = hb4[(size_t)i * 16 + q];
    float ps = (g == 0) ? eself : 0.f;
    float acc[8];
    acc[0] = ps * bf_lo(sv.x); acc[1] = ps * bf_hi(sv.x);
    acc[2] = ps * bf_lo(sv.y); acc[3] = ps * bf_hi(sv.y);
    acc[4] = ps * bf_lo(sv.z); acc[5] = ps * bf_hi(sv.z);
    acc[6] = ps * bf_lo(sv.w); acc[7] = ps * bf_hi(sv.w);
    float pacc = ps;
    for (int eb = e0; eb < e1; eb += 32) {
      uint2 mv[8];
#pragma unroll
      for (int k = 0; k < 8; ++k) {
        int idx = eb + (k << 2) + g;
        idx = idx < e1 ? idx : e1 - 1;
        mv[k] = meta[idx];
      }
      uint4 gv[8];
#pragma unroll
      for (int k = 0; k < 8; ++k) gv[k] = hb4[(size_t)mv[k].x * 16 + q];
#pragma unroll
      for (int k = 0; k < 8; ++k) {
        int idx = eb + (k << 2) + g;
        float pk = (idx < e1) ? __uint_as_float(mv[k].y) : 0.f;
        pacc += pk;
        acc[0] = fmaf(pk, bf_lo(gv[k].x), acc[0]);
        acc[1] = fmaf(pk, bf_hi(gv[k].x), acc[1]);
        acc[2] = fmaf(pk, bf_lo(gv[k].y), acc[2]);
        acc[3] = fmaf(pk, bf_hi(gv[k].y), acc[3]);
        acc[4] = fmaf(pk, bf_lo(gv[k].z), acc[4]);
        acc[5] = fmaf(pk, bf_hi(gv[k].z), acc[5]);
        acc[6] = fmaf(pk, bf_lo(gv[k].w), acc[6]);
        acc[7] = fmaf(pk, bf_hi(gv[k].w), acc[7]);
      }
    }
#pragma unroll
    for (int j = 0; j < 8; ++j) {
      acc[j] += __shfl_xor(acc[j], 16);
      acc[j] += __shfl_xor(acc[j], 32);
    }
    pacc += __shfl_xor(pacc, 16);
    pacc += __shfl_xor(pacc, 32);
    float inv = 1.0f / (pacc + 1e-16f);
    float o[8];
    o[0] = fmaf(acc[0], inv, bA.x); o[1] = fmaf(acc[1], inv, bA.y);
    o[2] = fmaf(acc[2], inv, bA.z); o[3] = fmaf(acc[3], inv, bA.w);
    o[4] = fmaf(acc[4], inv, bB.x); o[5] = fmaf(acc[5], inv, bB.y);
    o[6] = fmaf(acc[6], inv, bB.z); o[7] = fmaf(acc[7], inv, bB.w);
#pragma unroll
    for (int j = 0; j < 8; ++j) o[j] = o[j] > 0.f ? o[j] : 0.01f * o[j];
    if (g < 2) {
      float4 ov;
      if (g == 0) { ov.x = o[0]; ov.y = o[1]; ov.z = o[2]; ov.w = o[3]; }
      else { ov.x = o[4]; ov.y = o[5]; ov.z = o[6]; ov.w = o[7]; }
      *(float4*)(y + (size_t)i * 128 + (q << 3) + (g << 2)) = ov;
    }
    if (g == 0) {
#pragma unroll
      for (int j = 0; j < 8; ++j) {
        sS[j] += o[j];
        sQ[j] = fmaf(o[j], o[j], sQ[j]);
      }
    }
  }
  __shared__ float redS[4][16][8];
  __shared__ float redQ[4][16][8];
  if (g == 0) {
#pragma unroll
    for (int j = 0; j < 8; ++j) { redS[w][q][j] = sS[j]; redQ[w][q][j] = sQ[j]; }
  }
  __syncthreads();
  if (w == 0 && g == 0) {
#pragma unroll
    for (int j = 0; j < 8; ++j) {
      float a = (redS[0][q][j] + redS[1][q][j]) + (redS[2][q][j] + redS[3][q][j]);
      float c = (redQ[0][q][j] + redQ[1][q][j]) + (redQ[2][q][j] + redQ[3][q][j]);
      atomicAdd(&colsum[(q << 3) + j], a);
      atomicAdd(&colsumsq[(q << 3) + j], c);
    }
  }
}

__global__ void k_bnfinal(const float* __restrict__ colsum, const float* __restrict__ colsumsq,
                          const float* __restrict__ g, const float* __restrict__ be,
                          float invN, float* __restrict__ scale, float* __restrict__ shift) {
  int c = threadIdx.x;  // 128
  float mu = colsum[c] * invN;
  float var = colsumsq[c] * invN - mu * mu;
  var = var > 0.f ? var : 0.f;
  float sc = g[c] * rsqrtf(var + 1e-5f);
  scale[c] = sc;
  shift[c] = be[c] - mu * sc;
}

__global__ void k_bnapply(const float4* __restrict__ yin, const float* __restrict__ scale,
                          const float* __restrict__ shift, float4* __restrict__ yout, int total4) {
  int i = blockIdx.x * blockDim.x + threadIdx.x;
  if (i >= total4) return;
  int c4 = i & 31;
  float4 v = yin[i];
  float4 sc = ((const float4*)scale)[c4];
  float4 sh = ((const float4*)shift)[c4];
  v.x = fmaf(v.x, sc.x, sh.x);
  v.y = fmaf(v.y, sc.y, sh.y);
  v.z = fmaf(v.z, sc.z, sh.z);
  v.w = fmaf(v.w, sc.w, sh.w);
  yout[i] = v;
}

extern "C" void kernel_launch(void* const* d_in, const int* in_sizes, int n_in,
                              void* d_out, int out_size, void* d_ws, size_t ws_size,
                              hipStream_t stream) {
  const float* x = (const float*)d_in[0];
  const int* eidx = (const int*)d_in[1];
  const float* ea = (const float*)d_in[3];
  const int H = 128;
  const int N = in_sizes[0] / H;
  const int E = in_sizes[1] / 2;
  const int* srcIdx = eidx;
  const int* dstIdx = eidx + E;

  char* ws = (char*)d_ws;
  size_t off = 0;
  auto alloc = [&](size_t bytes) -> void* {
    void* p = ws + off;
    off = (off + bytes + 255) & ~(size_t)255;
    return p;
  };
  Edge* edges = (Edge*)alloc((size_t)E * sizeof(Edge));
  int* dsts = (int*)alloc((size_t)E * sizeof(int));
  uint2* meta = (uint2*)alloc((size_t)E * sizeof(uint2));
  unsigned* hb = (unsigned*)alloc((size_t)N * 64 * sizeof(unsigned));  // bf16 h
  float* y = (float*)alloc((size_t)N * H * sizeof(float));
  float* al_s = (float*)alloc((size_t)N * sizeof(float));
  float* al_d = (float*)alloc((size_t)N * sizeof(float));
  float* es = (float*)alloc((size_t)N * sizeof(float));
  int* deg = (int*)alloc((size_t)N * sizeof(int));
  int* start = (int*)alloc((size_t)(N + 1) * sizeof(int));
  int* cursor = (int*)alloc((size_t)N * sizeof(int));
  int* bsum = (int*)alloc(64 * sizeof(int));
  float* colstats = (float*)alloc(256 * sizeof(float));
  float* colsum = colstats;
  float* colsumsq = colstats + 128;
  float* scale = (float*)alloc(128 * sizeof(float));
  float* shift = (float*)alloc(128 * sizeof(float));
  float* ea_sum = (float*)alloc(16 * sizeof(float));
  float* P = (float*)alloc(16 * sizeof(float));

  const int nb = (N + 1023) / 1024;  // <= 64

  // ---- setup: sort edges by destination (CSR) ----
  hipMemsetAsync(deg, 0, (size_t)N * sizeof(int), stream);
  hipMemsetAsync(ea_sum, 0, 16 * sizeof(float), stream);
  k_hist<<<(E + 255) / 256, 256, 0, stream>>>(dstIdx, E, deg);
  k_ea_sum<<<256, 256, 0, stream>>>(ea, E, ea_sum);
  k_scan_a<<<nb, 1024, 0, stream>>>(deg, N, start, bsum);
  k_scan_b<<<1, 64, 0, stream>>>(bsum, nb, start, N);
  k_scan_c<<<(N + 255) / 256, 256, 0, stream>>>(start, bsum, N, cursor);
  k_scatter<<<(E + 255) / 256, 256, 0, stream>>>(srcIdx, dstIdx, ea, E, cursor, edges, dsts);
  k_initid<<<1, 128, 0, stream>>>(scale, shift);

  const float* X = x;
  for (int l = 0; l < 3; ++l) {
    const float* W = (const float*)d_in[4 + 8 * l + 0];
    const float* as = (const float*)d_in[4 + 8 * l + 1];
    const float* ad = (const float*)d_in[4 + 8 * l + 2];
    const float* We = (const float*)d_in[4 + 8 * l + 3];
    const float* ae = (const float*)d_in[4 + 8 * l + 4];
    const float* b = (const float*)d_in[4 + 8 * l + 5];
    const float* g = (const float*)d_in[4 + 8 * l + 6];
    const float* be = (const float*)d_in[4 + 8 * l + 7];

    hipMemsetAsync(colstats, 0, 256 * sizeof(float), stream);
    k_param<<<1, 64, 0, stream>>>(We, ae, ea_sum, 1.0f / (float)E, P);
    k_gemm2<<<512, 256, 0, stream>>>(X, W, scale, shift, as, ad, P, hb, al_s, al_d, es, N);
    k_alpha3<<<(E + 255) / 256, 256, 0, stream>>>((const float4*)edges, dsts, al_s, al_d, P,
                                                  meta, E);
    k_agg6<<<2048, 256, 0, stream>>>(meta, start, (const uint4*)hb, es, b, y,
                                     colsum, colsumsq, N);
    k_bnfinal<<<1, 128, 0, stream>>>(colsum, colsumsq, g, be, 1.0f / (float)N, scale, shift);
    X = y;
  }
  k_bnapply<<<((N * 32) + 255) / 256, 256, 0, stream>>>((const float4*)y, scale, shift,
                                                        (float4*)d_out, N * 32);
}

// Round 7
// 900.078 us; speedup vs baseline: 1.8288x; 1.8288x over previous
//
#include <hip/hip_runtime.h>
#include <math.h>

// ---------------------------------------------------------------------------
// GAT x3 + BN on MI355X.
//   setup:  fused hist(dst)+ea_sum -> 3-phase parallel scan -> counting-sort
//           edges (CSR).
//   layer:  k_gemm2: h = BN(X)@W (W in LDS, 4x4 reg tile), writes h as BF16,
//                    fused al_s/al_d/es epilogue
//           k_alpha2: pexp[e] = exp(lrelu(als[src]+ald[dst]+ale))
//           k_agg4: one wave/node, wave-uniform scalar meta loads, 8-deep
//                   unrolled bf16 row gathers (1 row/instr), 4 acc pairs,
//                   + bias + lrelu + BN partials   [R4 kernel, 125us/layer —
//                   R5 (shfl-broadcast) and R6 (4 rows/instr) both regressed:
//                   address divergence + VGPR pressure beat concurrency wins]
//           k_inter: BN finalize + zero stats + next layer's param (1 block)
//           k_bnapply_final: scale/shift from colstats in-block, apply -> out
// R7: revert agg to R4 optimum; fuse small dispatches (36 -> 19 launches).
// ---------------------------------------------------------------------------

struct __align__(16) Edge { int src; float e0, e1, e2; };

__device__ __forceinline__ unsigned short f2bf(float x) {
  unsigned u = __float_as_uint(x);
  unsigned r = (u + 0x7FFFu + ((u >> 16) & 1u)) >> 16;  // RNE
  return (unsigned short)r;
}
__device__ __forceinline__ float bf_lo(unsigned u) { return __uint_as_float(u << 16); }
__device__ __forceinline__ float bf_hi(unsigned u) { return __uint_as_float(u & 0xFFFF0000u); }

// fused: histogram of dst + column sums of edge_attr (one pass over E)
__global__ void k_hist_ea(const int* __restrict__ dst, const float* __restrict__ ea, int E,
                          int* __restrict__ deg, float* __restrict__ ea_sum) {
  int tid = blockIdx.x * blockDim.x + threadIdx.x;
  int stride = gridDim.x * blockDim.x;
  float s0 = 0.f, s1 = 0.f, s2 = 0.f;
  for (int i = tid; i < E; i += stride) {
    atomicAdd(&deg[dst[i]], 1);
    s0 += ea[i * 3 + 0]; s1 += ea[i * 3 + 1]; s2 += ea[i * 3 + 2];
  }
  for (int off = 32; off; off >>= 1) {
    s0 += __shfl_down(s0, off); s1 += __shfl_down(s1, off); s2 += __shfl_down(s2, off);
  }
  if ((threadIdx.x & 63) == 0) {
    atomicAdd(&ea_sum[0], s0); atomicAdd(&ea_sum[1], s1); atomicAdd(&ea_sum[2], s2);
  }
}

__device__ __forceinline__ int wave_incl_scan(int x, int lane) {
  for (int off = 1; off < 64; off <<= 1) {
    int t = __shfl_up(x, off);
    if (lane >= off) x += t;
  }
  return x;
}

__global__ __launch_bounds__(1024) void k_scan_a(const int* __restrict__ deg, int n,
                                                 int* __restrict__ start,
                                                 int* __restrict__ bsum) {
  __shared__ int wsum[16];
  int t = threadIdx.x, lane = t & 63, w = t >> 6;
  int i = blockIdx.x * 1024 + t;
  int v = (i < n) ? deg[i] : 0;
  int x = wave_incl_scan(v, lane);
  if (lane == 63) wsum[w] = x;
  __syncthreads();
  if (w == 0 && lane < 16) {
    int s = wsum[lane];
    for (int off = 1; off < 16; off <<= 1) {
      int u = __shfl_up(s, off);
      if (lane >= off) s += u;
    }
    wsum[lane] = s;
  }
  __syncthreads();
  int woff = w ? wsum[w - 1] : 0;
  if (i < n) start[i] = x - v + woff;
  if (t == 1023) bsum[blockIdx.x] = wsum[15];
}

__global__ void k_scan_b(int* __restrict__ bsum, int nb, int* __restrict__ start, int n) {
  int lane = threadIdx.x;  // 64
  int v = (lane < nb) ? bsum[lane] : 0;
  int x = wave_incl_scan(v, lane);
  if (lane < nb) bsum[lane] = x - v;
  if (lane == nb - 1) start[n] = x;
}

__global__ void k_scan_c(int* __restrict__ start, const int* __restrict__ bsum, int n,
                         int* __restrict__ cursor) {
  int i = blockIdx.x * blockDim.x + threadIdx.x;
  if (i < n) {
    int s = start[i] + bsum[i >> 10];
    start[i] = s;
    cursor[i] = s;
  }
}

__global__ void k_scatter(const int* __restrict__ src, const int* __restrict__ dst,
                          const float* __restrict__ ea, int E,
                          int* __restrict__ cursor, Edge* __restrict__ edges,
                          int* __restrict__ srcs, int* __restrict__ dsts) {
  int i = blockIdx.x * blockDim.x + threadIdx.x;
  if (i >= E) return;
  int d = dst[i];
  int pos = atomicAdd(&cursor[d], 1);
  Edge e;
  int s = src[i];
  e.src = s;
  e.e0 = ea[i * 3 + 0]; e.e1 = ea[i * 3 + 1]; e.e2 = ea[i * 3 + 2];
  edges[pos] = e;
  srcs[pos] = s;
  dsts[pos] = d;
}

__device__ __forceinline__ void param_wave(const float* __restrict__ We,
                                           const float* __restrict__ ae,
                                           const float* __restrict__ ea_sum, float invE,
                                           float* __restrict__ P, int lane) {
  float a0 = ae[lane], a1 = ae[64 + lane];
  float p0 = We[0 * 128 + lane] * a0 + We[0 * 128 + 64 + lane] * a1;
  float p1 = We[1 * 128 + lane] * a0 + We[1 * 128 + 64 + lane] * a1;
  float p2 = We[2 * 128 + lane] * a0 + We[2 * 128 + 64 + lane] * a1;
  for (int off = 32; off; off >>= 1) {
    p0 += __shfl_down(p0, off); p1 += __shfl_down(p1, off); p2 += __shfl_down(p2, off);
  }
  if (lane == 0) {
    P[0] = p0; P[1] = p1; P[2] = p2;
    P[3] = ea_sum[0] * invE * p0 + ea_sum[1] * invE * p1 + ea_sum[2] * invE * p2;
  }
}

// one block, 192 threads: wave0 = layer-0 param; threads 64..191 = identity
// BN scale/shift + zero colstats
__global__ void k_param0(const float* __restrict__ We, const float* __restrict__ ae,
                         const float* __restrict__ ea_sum, float invE, float* __restrict__ P,
                         float* __restrict__ scale, float* __restrict__ shift,
                         float* __restrict__ colstats) {
  int t = threadIdx.x;
  if (t < 64) {
    param_wave(We, ae, ea_sum, invE, P, t);
  } else if (t < 192) {
    int c = t - 64;
    scale[c] = 1.f; shift[c] = 0.f;
    colstats[c] = 0.f; colstats[128 + c] = 0.f;
  }
}

// one block, 192 threads: wave0 = NEXT layer's param; threads 64..191 =
// BN finalize (colstats -> scale/shift) + zero colstats for next layer
__global__ void k_inter(const float* __restrict__ colstatsIn, const float* __restrict__ g,
                        const float* __restrict__ be, float invN,
                        float* __restrict__ scale, float* __restrict__ shift,
                        const float* __restrict__ WeN, const float* __restrict__ aeN,
                        const float* __restrict__ ea_sum, float invE, float* __restrict__ P,
                        float* __restrict__ colstats) {
  int t = threadIdx.x;
  if (t < 64) {
    param_wave(WeN, aeN, ea_sum, invE, P, t);
  } else if (t < 192) {
    int c = t - 64;
    float mu = colstatsIn[c] * invN;
    float var = colstatsIn[128 + c] * invN - mu * mu;
    var = var > 0.f ? var : 0.f;
    float sc = g[c] * rsqrtf(var + 1e-5f);
    scale[c] = sc;
    shift[c] = be[c] - mu * sc;
    colstats[c] = 0.f; colstats[128 + c] = 0.f;
  }
}

// h[N,128] = (X*bnsc+bnsh) @ W, stored as bf16 rows (256 B).  W in LDS,
// 32-row tiles, 4 rows x 4 cols per thread.  Fused al_s/al_d/es epilogue.
__global__ __launch_bounds__(256) void k_gemm2(
    const float* __restrict__ X, const float* __restrict__ Wm,
    const float* __restrict__ bnsc, const float* __restrict__ bnsh,
    const float* __restrict__ as, const float* __restrict__ ad,
    const float* __restrict__ P,
    unsigned* __restrict__ hb, float* __restrict__ al_s, float* __restrict__ al_d,
    float* __restrict__ es, int n) {
  __shared__ float wl[128 * 128];
  __shared__ float xs[32 * 128];
  int t = threadIdx.x;
  for (int i = t; i < 4096; i += 256) ((float4*)wl)[i] = ((const float4*)Wm)[i];
  int c32 = t & 31;
  int c4 = c32 << 2;
  int rq = t >> 5;
  int lane = t & 63;
  float4 av_s = *(const float4*)(as + c4);
  float4 av_d = *(const float4*)(ad + c4);
  float cself = P[3];
  int ntiles = (n + 31) >> 5;
  for (int tile = blockIdx.x; tile < ntiles; tile += gridDim.x) {
    int r0 = tile << 5;
    __syncthreads();
    for (int i = t; i < 1024; i += 256) {
      int rr = i >> 5, cc = i & 31;
      int g = r0 + rr;
      float4 v;
      if (g < n) {
        v = ((const float4*)(X + (size_t)g * 128))[cc];
        float4 sc = ((const float4*)bnsc)[cc];
        float4 sh = ((const float4*)bnsh)[cc];
        v.x = fmaf(v.x, sc.x, sh.x); v.y = fmaf(v.y, sc.y, sh.y);
        v.z = fmaf(v.z, sc.z, sh.z); v.w = fmaf(v.w, sc.w, sh.w);
      } else { v.x = v.y = v.z = v.w = 0.f; }
      ((float4*)xs)[i] = v;
    }
    __syncthreads();
    float4 acc[4];
    for (int r = 0; r < 4; ++r) { acc[r].x = acc[r].y = acc[r].z = acc[r].w = 0.f; }
    const float* xr = xs + (rq << 2) * 128;
#pragma unroll 4
    for (int k = 0; k < 128; ++k) {
      float4 w4 = ((const float4*)wl)[(k << 5) + c32];
#pragma unroll
      for (int r = 0; r < 4; ++r) {
        float xv = xr[r * 128 + k];
        acc[r].x = fmaf(xv, w4.x, acc[r].x);
        acc[r].y = fmaf(xv, w4.y, acc[r].y);
        acc[r].z = fmaf(xv, w4.z, acc[r].z);
        acc[r].w = fmaf(xv, w4.w, acc[r].w);
      }
    }
    int gbase = r0 + (rq << 2);
#pragma unroll
    for (int r = 0; r < 4; ++r) {
      int g = gbase + r;
      float4 o = acc[r];
      if (g < n) {
        unsigned u01 = ((unsigned)f2bf(o.y) << 16) | (unsigned)f2bf(o.x);
        unsigned u23 = ((unsigned)f2bf(o.w) << 16) | (unsigned)f2bf(o.z);
        uint2 uu = {u01, u23};
        *(uint2*)(hb + (size_t)g * 64 + (c32 << 1)) = uu;
      }
      float ps = o.x * av_s.x + o.y * av_s.y + o.z * av_s.z + o.w * av_s.w;
      float pd = o.x * av_d.x + o.y * av_d.y + o.z * av_d.z + o.w * av_d.w;
      for (int off = 16; off; off >>= 1) {
        ps += __shfl_xor(ps, off);
        pd += __shfl_xor(pd, off);
      }
      if ((lane & 31) == 0 && g < n) {
        al_s[g] = ps; al_d[g] = pd;
        float a = ps + pd + cself;
        a = a > 0.f ? a : 0.2f * a;
        es[g] = __expf(a);
      }
    }
  }
}

// flat per-edge: pexp[e] = exp(lrelu_0.2(al_s[src] + al_d[dst] + ea.We@ae))
__global__ __launch_bounds__(256) void k_alpha2(const float4* __restrict__ edges,
                                                const int* __restrict__ dsts,
                                                const float* __restrict__ al_s,
                                                const float* __restrict__ al_d,
                                                const float* __restrict__ P,
                                                float* __restrict__ pexp, int E) {
  int i = blockIdx.x * blockDim.x + threadIdx.x;
  if (i >= E) return;
  float4 ef = edges[i];
  int s = __float_as_int(ef.x);
  float a = al_s[s] + al_d[dsts[i]] + ef.y * P[0] + ef.z * P[1] + ef.w * P[2];
  a = a > 0.f ? a : 0.2f * a;
  pexp[i] = __expf(a);
}

// one wave per node.  Edge meta (srcs, pexp) via wave-uniform loads; p is
// identical in all lanes so the denominator needs no reduction.  bf16 row
// gathers (lane reads 4 B = 2 features), 8-deep unroll, 4 acc pairs.
__global__ __launch_bounds__(256) void k_agg4(const int* __restrict__ srcs,
                                              const float* __restrict__ pexp,
                                              const int* __restrict__ start,
                                              const unsigned* __restrict__ hb,
                                              const float* __restrict__ es,
                                              const float* __restrict__ bias,
                                              float* __restrict__ y,
                                              float* __restrict__ colsum,
                                              float* __restrict__ colsumsq, int n) {
  int lane = threadIdx.x & 63;
  int w = threadIdx.x >> 6;
  int gw = (blockIdx.x * blockDim.x + threadIdx.x) >> 6;
  int nw = (gridDim.x * blockDim.x) >> 6;
  float2 b2 = ((const float2*)bias)[lane];
  float s0 = 0.f, s1 = 0.f, q0 = 0.f, q1 = 0.f;
  for (int i = gw; i < n; i += nw) {
    int e0 = __builtin_amdgcn_readfirstlane(start[i]);
    int e1 = __builtin_amdgcn_readfirstlane(start[i + 1]);
    float eself = es[i];
    unsigned hv = hb[(size_t)i * 64 + lane];
    float aX0 = eself * bf_lo(hv), aY0 = eself * bf_hi(hv);
    float aX1 = 0.f, aY1 = 0.f, aX2 = 0.f, aY2 = 0.f, aX3 = 0.f, aY3 = 0.f;
    float pacc = 0.f;
    int e = e0;
    for (; e + 8 <= e1; e += 8) {
      int sv[8]; float pv[8]; unsigned gv[8];
#pragma unroll
      for (int k = 0; k < 8; ++k) sv[k] = srcs[e + k];
#pragma unroll
      for (int k = 0; k < 8; ++k) pv[k] = pexp[e + k];
#pragma unroll
      for (int k = 0; k < 8; ++k) gv[k] = hb[(size_t)sv[k] * 64 + lane];
#pragma unroll
      for (int k = 0; k < 8; ++k) {
        float gx = bf_lo(gv[k]);
        float gy = bf_hi(gv[k]);
        pacc += pv[k];
        if ((k & 3) == 0) { aX0 = fmaf(pv[k], gx, aX0); aY0 = fmaf(pv[k], gy, aY0); }
        else if ((k & 3) == 1) { aX1 = fmaf(pv[k], gx, aX1); aY1 = fmaf(pv[k], gy, aY1); }
        else if ((k & 3) == 2) { aX2 = fmaf(pv[k], gx, aX2); aY2 = fmaf(pv[k], gy, aY2); }
        else { aX3 = fmaf(pv[k], gx, aX3); aY3 = fmaf(pv[k], gy, aY3); }
      }
    }
    for (; e < e1; ++e) {
      int sv = srcs[e];
      float pv = pexp[e];
      unsigned gv = hb[(size_t)sv * 64 + lane];
      float gx = bf_lo(gv);
      float gy = bf_hi(gv);
      pacc += pv;
      aX0 = fmaf(pv, gx, aX0); aY0 = fmaf(pv, gy, aY0);
    }
    float inv = 1.0f / (eself + pacc + 1e-16f);
    float o0 = (aX0 + aX1) + (aX2 + aX3);
    float o1 = (aY0 + aY1) + (aY2 + aY3);
    o0 = fmaf(o0, inv, b2.x);
    o1 = fmaf(o1, inv, b2.y);
    o0 = o0 > 0.f ? o0 : 0.01f * o0;
    o1 = o1 > 0.f ? o1 : 0.01f * o1;
    float2 o2 = {o0, o1};
    ((float2*)(y + (size_t)i * 128))[lane] = o2;
    s0 += o0; s1 += o1;
    q0 = fmaf(o0, o0, q0); q1 = fmaf(o1, o1, q1);
  }
  __shared__ float red[4][4][64];
  red[0][w][lane] = s0; red[1][w][lane] = s1; red[2][w][lane] = q0; red[3][w][lane] = q1;
  __syncthreads();
  if (w == 0) {
    for (int ww = 1; ww < 4; ++ww) {
      s0 += red[0][ww][lane]; s1 += red[1][ww][lane];
      q0 += red[2][ww][lane]; q1 += red[3][ww][lane];
    }
    atomicAdd(&colsum[2 * lane], s0);
    atomicAdd(&colsum[2 * lane + 1], s1);
    atomicAdd(&colsumsq[2 * lane], q0);
    atomicAdd(&colsumsq[2 * lane + 1], q1);
  }
}

// final BN: compute scale/shift from colstats in-block, then apply y -> out
__global__ __launch_bounds__(256) void k_bnapply_final(
    const float4* __restrict__ yin, const float* __restrict__ colstats,
    const float* __restrict__ g, const float* __restrict__ be, float invN,
    float4* __restrict__ yout, int total4) {
  __shared__ float sc_s[128], sh_s[128];
  int t = threadIdx.x;
  if (t < 128) {
    float mu = colstats[t] * invN;
    float var = colstats[128 + t] * invN - mu * mu;
    var = var > 0.f ? var : 0.f;
    float sc = g[t] * rsqrtf(var + 1e-5f);
    sc_s[t] = sc;
    sh_s[t] = be[t] - mu * sc;
  }
  __syncthreads();
  for (int i = blockIdx.x * blockDim.x + t; i < total4; i += gridDim.x * blockDim.x) {
    int c4 = (i & 31) << 2;
    float4 v = yin[i];
    v.x = fmaf(v.x, sc_s[c4 + 0], sh_s[c4 + 0]);
    v.y = fmaf(v.y, sc_s[c4 + 1], sh_s[c4 + 1]);
    v.z = fmaf(v.z, sc_s[c4 + 2], sh_s[c4 + 2]);
    v.w = fmaf(v.w, sc_s[c4 + 3], sh_s[c4 + 3]);
    yout[i] = v;
  }
}

extern "C" void kernel_launch(void* const* d_in, const int* in_sizes, int n_in,
                              void* d_out, int out_size, void* d_ws, size_t ws_size,
                              hipStream_t stream) {
  const float* x = (const float*)d_in[0];
  const int* eidx = (const int*)d_in[1];
  const float* ea = (const float*)d_in[3];
  const int H = 128;
  const int N = in_sizes[0] / H;
  const int E = in_sizes[1] / 2;
  const int* srcIdx = eidx;
  const int* dstIdx = eidx + E;

  char* ws = (char*)d_ws;
  size_t off = 0;
  auto alloc = [&](size_t bytes) -> void* {
    void* p = ws + off;
    off = (off + bytes + 255) & ~(size_t)255;
    return p;
  };
  Edge* edges = (Edge*)alloc((size_t)E * sizeof(Edge));
  int* srcs = (int*)alloc((size_t)E * sizeof(int));
  int* dsts = (int*)alloc((size_t)E * sizeof(int));
  float* pexp = (float*)alloc((size_t)E * sizeof(float));
  unsigned* hb = (unsigned*)alloc((size_t)N * 64 * sizeof(unsigned));  // bf16 h
  float* y = (float*)alloc((size_t)N * H * sizeof(float));
  float* al_s = (float*)alloc((size_t)N * sizeof(float));
  float* al_d = (float*)alloc((size_t)N * sizeof(float));
  float* es = (float*)alloc((size_t)N * sizeof(float));
  // deg and ea_sum in one region -> one memset
  int* deg = (int*)alloc((size_t)(N + 64) * sizeof(int));
  float* ea_sum = (float*)(deg + N);
  int* start = (int*)alloc((size_t)(N + 1) * sizeof(int));
  int* cursor = (int*)alloc((size_t)N * sizeof(int));
  int* bsum = (int*)alloc(64 * sizeof(int));
  float* colstats = (float*)alloc(256 * sizeof(float));
  float* colsum = colstats;
  float* colsumsq = colstats + 128;
  float* scale = (float*)alloc(128 * sizeof(float));
  float* shift = (float*)alloc(128 * sizeof(float));
  float* P = (float*)alloc(16 * sizeof(float));

  const int nb = (N + 1023) / 1024;  // <= 64
  const float invE = 1.0f / (float)E;
  const float invN = 1.0f / (float)N;

  // ---- setup: sort edges by destination (CSR) ----
  hipMemsetAsync(deg, 0, (size_t)(N + 64) * sizeof(int), stream);
  k_hist_ea<<<1024, 256, 0, stream>>>(dstIdx, ea, E, deg, ea_sum);
  k_scan_a<<<nb, 1024, 0, stream>>>(deg, N, start, bsum);
  k_scan_b<<<1, 64, 0, stream>>>(bsum, nb, start, N);
  k_scan_c<<<(N + 255) / 256, 256, 0, stream>>>(start, bsum, N, cursor);
  k_scatter<<<(E + 255) / 256, 256, 0, stream>>>(srcIdx, dstIdx, ea, E, cursor, edges, srcs, dsts);

  // layer parameter pointers
  const float* Wl[3]; const float* asl[3]; const float* adl[3]; const float* Wel[3];
  const float* ael[3]; const float* bl[3]; const float* gl[3]; const float* bel[3];
  for (int l = 0; l < 3; ++l) {
    Wl[l] = (const float*)d_in[4 + 8 * l + 0];
    asl[l] = (const float*)d_in[4 + 8 * l + 1];
    adl[l] = (const float*)d_in[4 + 8 * l + 2];
    Wel[l] = (const float*)d_in[4 + 8 * l + 3];
    ael[l] = (const float*)d_in[4 + 8 * l + 4];
    bl[l] = (const float*)d_in[4 + 8 * l + 5];
    gl[l] = (const float*)d_in[4 + 8 * l + 6];
    bel[l] = (const float*)d_in[4 + 8 * l + 7];
  }

  k_param0<<<1, 192, 0, stream>>>(Wel[0], ael[0], ea_sum, invE, P, scale, shift, colstats);

  const float* X = x;
  for (int l = 0; l < 3; ++l) {
    k_gemm2<<<512, 256, 0, stream>>>(X, Wl[l], scale, shift, asl[l], adl[l], P,
                                     hb, al_s, al_d, es, N);
    k_alpha2<<<(E + 255) / 256, 256, 0, stream>>>((const float4*)edges, dsts, al_s, al_d, P,
                                                  pexp, E);
    k_agg4<<<2048, 256, 0, stream>>>(srcs, pexp, start, hb, es, bl[l], y,
                                     colsum, colsumsq, N);
    if (l < 2) {
      // BN finalize for layer l + param for layer l+1 + zero colstats
      k_inter<<<1, 192, 0, stream>>>(colstats, gl[l], bel[l], invN, scale, shift,
                                     Wel[l + 1], ael[l + 1], ea_sum, invE, P, colstats);
    }
    X = y;
  }
  k_bnapply_final<<<384, 256, 0, stream>>>((const float4*)y, colstats, gl[2], bel[2], invN,
                                           (float4*)d_out, N * 32);
}

// Round 8
// 888.806 us; speedup vs baseline: 1.8520x; 1.0127x over previous
//
#include <hip/hip_runtime.h>
#include <math.h>

// ---------------------------------------------------------------------------
// GAT x3 + BN on MI355X.
//   setup:  k_hist_ea8: per-XCD-replica histogram (blockIdx&7 ~ XCD; atomics
//           stay in the local L2 -> no cross-XCD line ping-pong) + ea col sums
//           -> scan (sums 8 replicas) -> per-replica cursors -> scatter with
//           XCD-local cursor atomics -> CSR.
//   layer:  k_gemm2: h = BN(X)@W (W in LDS, 4x4 reg tile), writes h as BF16,
//                    fused al_s/al_d/es epilogue
//           k_alpha2: pexp[e] = exp(lrelu(als[src]+ald[dst]+ale))
//           k_agg4: one wave/node, wave-uniform scalar meta loads, 8-deep
//                   unrolled bf16 row gathers, 4 acc pairs, + bias+lrelu+BN
//                   [R4 shape = measured local optimum; R5/R6 variants regressed]
//           k_inter: BN finalize + zero stats + next layer's param (1 block)
//           k_bnapply_final: scale/shift from colstats in-block, apply -> out
// R8: R7 exposed k_hist_ea at 181us with WRITE_SIZE=25MB for a 200KB output
// = atomic cache-line migration across XCDs.  Replicated XCD-local atomics
// for hist + scatter cursors.
// ---------------------------------------------------------------------------

#define NREP 8

struct __align__(16) Edge { int src; float e0, e1, e2; };

__device__ __forceinline__ unsigned short f2bf(float x) {
  unsigned u = __float_as_uint(x);
  unsigned r = (u + 0x7FFFu + ((u >> 16) & 1u)) >> 16;  // RNE
  return (unsigned short)r;
}
__device__ __forceinline__ float bf_lo(unsigned u) { return __uint_as_float(u << 16); }
__device__ __forceinline__ float bf_hi(unsigned u) { return __uint_as_float(u & 0xFFFF0000u); }

// replicated histogram (replica = blockIdx&7 ~ XCD) + ea column sums
__global__ void k_hist_ea8(const int* __restrict__ dst, const float* __restrict__ ea, int E,
                           int* __restrict__ deg8, int n, float* __restrict__ ea_sum) {
  int* degr = deg8 + (size_t)(blockIdx.x & (NREP - 1)) * n;
  int tid = blockIdx.x * blockDim.x + threadIdx.x;
  int stride = gridDim.x * blockDim.x;
  float s0 = 0.f, s1 = 0.f, s2 = 0.f;
  for (int i = tid; i < E; i += stride) {
    atomicAdd(&degr[dst[i]], 1);
    s0 += ea[i * 3 + 0]; s1 += ea[i * 3 + 1]; s2 += ea[i * 3 + 2];
  }
  for (int off = 32; off; off >>= 1) {
    s0 += __shfl_down(s0, off); s1 += __shfl_down(s1, off); s2 += __shfl_down(s2, off);
  }
  if ((threadIdx.x & 63) == 0) {
    atomicAdd(&ea_sum[0], s0); atomicAdd(&ea_sum[1], s1); atomicAdd(&ea_sum[2], s2);
  }
}

__device__ __forceinline__ int wave_incl_scan(int x, int lane) {
  for (int off = 1; off < 64; off <<= 1) {
    int t = __shfl_up(x, off);
    if (lane >= off) x += t;
  }
  return x;
}

// phase A: sum 8 replicas -> per-block exclusive scan -> start[], block sums
__global__ __launch_bounds__(1024) void k_scan_a(const int* __restrict__ deg8, int n,
                                                 int* __restrict__ start,
                                                 int* __restrict__ bsum) {
  __shared__ int wsum[16];
  int t = threadIdx.x, lane = t & 63, w = t >> 6;
  int i = blockIdx.x * 1024 + t;
  int v = 0;
  if (i < n) {
#pragma unroll
    for (int r = 0; r < NREP; ++r) v += deg8[(size_t)r * n + i];
  }
  int x = wave_incl_scan(v, lane);
  if (lane == 63) wsum[w] = x;
  __syncthreads();
  if (w == 0 && lane < 16) {
    int s = wsum[lane];
    for (int off = 1; off < 16; off <<= 1) {
      int u = __shfl_up(s, off);
      if (lane >= off) s += u;
    }
    wsum[lane] = s;
  }
  __syncthreads();
  int woff = w ? wsum[w - 1] : 0;
  if (i < n) start[i] = x - v + woff;
  if (t == 1023) bsum[blockIdx.x] = wsum[15];
}

__global__ void k_scan_b(int* __restrict__ bsum, int nb, int* __restrict__ start, int n) {
  int lane = threadIdx.x;  // 64
  int v = (lane < nb) ? bsum[lane] : 0;
  int x = wave_incl_scan(v, lane);
  if (lane < nb) bsum[lane] = x - v;
  if (lane == nb - 1) start[n] = x;
}

// phase C: finalize start; emit per-replica cursor planes
__global__ void k_scan_c(int* __restrict__ start, const int* __restrict__ bsum,
                         const int* __restrict__ deg8, int n, int* __restrict__ cursor8) {
  int i = blockIdx.x * blockDim.x + threadIdx.x;
  if (i < n) {
    int s = start[i] + bsum[i >> 10];
    start[i] = s;
    int run = s;
#pragma unroll
    for (int r = 0; r < NREP; ++r) {
      cursor8[(size_t)r * n + i] = run;
      run += deg8[(size_t)r * n + i];
    }
  }
}

// scatter with XCD-local cursor atomics (replica = blockIdx&7, matches hist)
__global__ void k_scatter8(const int* __restrict__ src, const int* __restrict__ dst,
                           const float* __restrict__ ea, int E, int n,
                           int* __restrict__ cursor8, Edge* __restrict__ edges,
                           int* __restrict__ srcs, int* __restrict__ dsts) {
  int* curr = cursor8 + (size_t)(blockIdx.x & (NREP - 1)) * n;
  int tid = blockIdx.x * blockDim.x + threadIdx.x;
  int stride = gridDim.x * blockDim.x;
  for (int i = tid; i < E; i += stride) {
    int d = dst[i];
    int pos = atomicAdd(&curr[d], 1);
    Edge e;
    int s = src[i];
    e.src = s;
    e.e0 = ea[i * 3 + 0]; e.e1 = ea[i * 3 + 1]; e.e2 = ea[i * 3 + 2];
    edges[pos] = e;
    srcs[pos] = s;
    dsts[pos] = d;
  }
}

__device__ __forceinline__ void param_wave(const float* __restrict__ We,
                                           const float* __restrict__ ae,
                                           const float* __restrict__ ea_sum, float invE,
                                           float* __restrict__ P, int lane) {
  float a0 = ae[lane], a1 = ae[64 + lane];
  float p0 = We[0 * 128 + lane] * a0 + We[0 * 128 + 64 + lane] * a1;
  float p1 = We[1 * 128 + lane] * a0 + We[1 * 128 + 64 + lane] * a1;
  float p2 = We[2 * 128 + lane] * a0 + We[2 * 128 + 64 + lane] * a1;
  for (int off = 32; off; off >>= 1) {
    p0 += __shfl_down(p0, off); p1 += __shfl_down(p1, off); p2 += __shfl_down(p2, off);
  }
  if (lane == 0) {
    P[0] = p0; P[1] = p1; P[2] = p2;
    P[3] = ea_sum[0] * invE * p0 + ea_sum[1] * invE * p1 + ea_sum[2] * invE * p2;
  }
}

__global__ void k_param0(const float* __restrict__ We, const float* __restrict__ ae,
                         const float* __restrict__ ea_sum, float invE, float* __restrict__ P,
                         float* __restrict__ scale, float* __restrict__ shift,
                         float* __restrict__ colstats) {
  int t = threadIdx.x;
  if (t < 64) {
    param_wave(We, ae, ea_sum, invE, P, t);
  } else if (t < 192) {
    int c = t - 64;
    scale[c] = 1.f; shift[c] = 0.f;
    colstats[c] = 0.f; colstats[128 + c] = 0.f;
  }
}

__global__ void k_inter(const float* __restrict__ colstatsIn, const float* __restrict__ g,
                        const float* __restrict__ be, float invN,
                        float* __restrict__ scale, float* __restrict__ shift,
                        const float* __restrict__ WeN, const float* __restrict__ aeN,
                        const float* __restrict__ ea_sum, float invE, float* __restrict__ P,
                        float* __restrict__ colstats) {
  int t = threadIdx.x;
  if (t < 64) {
    param_wave(WeN, aeN, ea_sum, invE, P, t);
  } else if (t < 192) {
    int c = t - 64;
    float mu = colstatsIn[c] * invN;
    float var = colstatsIn[128 + c] * invN - mu * mu;
    var = var > 0.f ? var : 0.f;
    float sc = g[c] * rsqrtf(var + 1e-5f);
    scale[c] = sc;
    shift[c] = be[c] - mu * sc;
    colstats[c] = 0.f; colstats[128 + c] = 0.f;
  }
}

// h[N,128] = (X*bnsc+bnsh) @ W, stored as bf16 rows (256 B).  W in LDS,
// 32-row tiles, 4 rows x 4 cols per thread.  Fused al_s/al_d/es epilogue.
__global__ __launch_bounds__(256) void k_gemm2(
    const float* __restrict__ X, const float* __restrict__ Wm,
    const float* __restrict__ bnsc, const float* __restrict__ bnsh,
    const float* __restrict__ as, const float* __restrict__ ad,
    const float* __restrict__ P,
    unsigned* __restrict__ hb, float* __restrict__ al_s, float* __restrict__ al_d,
    float* __restrict__ es, int n) {
  __shared__ float wl[128 * 128];
  __shared__ float xs[32 * 128];
  int t = threadIdx.x;
  for (int i = t; i < 4096; i += 256) ((float4*)wl)[i] = ((const float4*)Wm)[i];
  int c32 = t & 31;
  int c4 = c32 << 2;
  int rq = t >> 5;
  int lane = t & 63;
  float4 av_s = *(const float4*)(as + c4);
  float4 av_d = *(const float4*)(ad + c4);
  float cself = P[3];
  int ntiles = (n + 31) >> 5;
  for (int tile = blockIdx.x; tile < ntiles; tile += gridDim.x) {
    int r0 = tile << 5;
    __syncthreads();
    for (int i = t; i < 1024; i += 256) {
      int rr = i >> 5, cc = i & 31;
      int g = r0 + rr;
      float4 v;
      if (g < n) {
        v = ((const float4*)(X + (size_t)g * 128))[cc];
        float4 sc = ((const float4*)bnsc)[cc];
        float4 sh = ((const float4*)bnsh)[cc];
        v.x = fmaf(v.x, sc.x, sh.x); v.y = fmaf(v.y, sc.y, sh.y);
        v.z = fmaf(v.z, sc.z, sh.z); v.w = fmaf(v.w, sc.w, sh.w);
      } else { v.x = v.y = v.z = v.w = 0.f; }
      ((float4*)xs)[i] = v;
    }
    __syncthreads();
    float4 acc[4];
    for (int r = 0; r < 4; ++r) { acc[r].x = acc[r].y = acc[r].z = acc[r].w = 0.f; }
    const float* xr = xs + (rq << 2) * 128;
#pragma unroll 4
    for (int k = 0; k < 128; ++k) {
      float4 w4 = ((const float4*)wl)[(k << 5) + c32];
#pragma unroll
      for (int r = 0; r < 4; ++r) {
        float xv = xr[r * 128 + k];
        acc[r].x = fmaf(xv, w4.x, acc[r].x);
        acc[r].y = fmaf(xv, w4.y, acc[r].y);
        acc[r].z = fmaf(xv, w4.z, acc[r].z);
        acc[r].w = fmaf(xv, w4.w, acc[r].w);
      }
    }
    int gbase = r0 + (rq << 2);
#pragma unroll
    for (int r = 0; r < 4; ++r) {
      int g = gbase + r;
      float4 o = acc[r];
      if (g < n) {
        unsigned u01 = ((unsigned)f2bf(o.y) << 16) | (unsigned)f2bf(o.x);
        unsigned u23 = ((unsigned)f2bf(o.w) << 16) | (unsigned)f2bf(o.z);
        uint2 uu = {u01, u23};
        *(uint2*)(hb + (size_t)g * 64 + (c32 << 1)) = uu;
      }
      float ps = o.x * av_s.x + o.y * av_s.y + o.z * av_s.z + o.w * av_s.w;
      float pd = o.x * av_d.x + o.y * av_d.y + o.z * av_d.z + o.w * av_d.w;
      for (int off = 16; off; off >>= 1) {
        ps += __shfl_xor(ps, off);
        pd += __shfl_xor(pd, off);
      }
      if ((lane & 31) == 0 && g < n) {
        al_s[g] = ps; al_d[g] = pd;
        float a = ps + pd + cself;
        a = a > 0.f ? a : 0.2f * a;
        es[g] = __expf(a);
      }
    }
  }
}

// flat per-edge: pexp[e] = exp(lrelu_0.2(al_s[src] + al_d[dst] + ea.We@ae))
__global__ __launch_bounds__(256) void k_alpha2(const float4* __restrict__ edges,
                                                const int* __restrict__ dsts,
                                                const float* __restrict__ al_s,
                                                const float* __restrict__ al_d,
                                                const float* __restrict__ P,
                                                float* __restrict__ pexp, int E) {
  int i = blockIdx.x * blockDim.x + threadIdx.x;
  if (i >= E) return;
  float4 ef = edges[i];
  int s = __float_as_int(ef.x);
  float a = al_s[s] + al_d[dsts[i]] + ef.y * P[0] + ef.z * P[1] + ef.w * P[2];
  a = a > 0.f ? a : 0.2f * a;
  pexp[i] = __expf(a);
}

// one wave per node.  Edge meta (srcs, pexp) via wave-uniform loads; p is
// identical in all lanes so the denominator needs no reduction.  bf16 row
// gathers (lane reads 4 B = 2 features), 8-deep unroll, 4 acc pairs.
__global__ __launch_bounds__(256) void k_agg4(const int* __restrict__ srcs,
                                              const float* __restrict__ pexp,
                                              const int* __restrict__ start,
                                              const unsigned* __restrict__ hb,
                                              const float* __restrict__ es,
                                              const float* __restrict__ bias,
                                              float* __restrict__ y,
                                              float* __restrict__ colsum,
                                              float* __restrict__ colsumsq, int n) {
  int lane = threadIdx.x & 63;
  int w = threadIdx.x >> 6;
  int gw = (blockIdx.x * blockDim.x + threadIdx.x) >> 6;
  int nw = (gridDim.x * blockDim.x) >> 6;
  float2 b2 = ((const float2*)bias)[lane];
  float s0 = 0.f, s1 = 0.f, q0 = 0.f, q1 = 0.f;
  for (int i = gw; i < n; i += nw) {
    int e0 = __builtin_amdgcn_readfirstlane(start[i]);
    int e1 = __builtin_amdgcn_readfirstlane(start[i + 1]);
    float eself = es[i];
    unsigned hv = hb[(size_t)i * 64 + lane];
    float aX0 = eself * bf_lo(hv), aY0 = eself * bf_hi(hv);
    float aX1 = 0.f, aY1 = 0.f, aX2 = 0.f, aY2 = 0.f, aX3 = 0.f, aY3 = 0.f;
    float pacc = 0.f;
    int e = e0;
    for (; e + 8 <= e1; e += 8) {
      int sv[8]; float pv[8]; unsigned gv[8];
#pragma unroll
      for (int k = 0; k < 8; ++k) sv[k] = srcs[e + k];
#pragma unroll
      for (int k = 0; k < 8; ++k) pv[k] = pexp[e + k];
#pragma unroll
      for (int k = 0; k < 8; ++k) gv[k] = hb[(size_t)sv[k] * 64 + lane];
#pragma unroll
      for (int k = 0; k < 8; ++k) {
        float gx = bf_lo(gv[k]);
        float gy = bf_hi(gv[k]);
        pacc += pv[k];
        if ((k & 3) == 0) { aX0 = fmaf(pv[k], gx, aX0); aY0 = fmaf(pv[k], gy, aY0); }
        else if ((k & 3) == 1) { aX1 = fmaf(pv[k], gx, aX1); aY1 = fmaf(pv[k], gy, aY1); }
        else if ((k & 3) == 2) { aX2 = fmaf(pv[k], gx, aX2); aY2 = fmaf(pv[k], gy, aY2); }
        else { aX3 = fmaf(pv[k], gx, aX3); aY3 = fmaf(pv[k], gy, aY3); }
      }
    }
    for (; e < e1; ++e) {
      int sv = srcs[e];
      float pv = pexp[e];
      unsigned gv = hb[(size_t)sv * 64 + lane];
      float gx = bf_lo(gv);
      float gy = bf_hi(gv);
      pacc += pv;
      aX0 = fmaf(pv, gx, aX0); aY0 = fmaf(pv, gy, aY0);
    }
    float inv = 1.0f / (eself + pacc + 1e-16f);
    float o0 = (aX0 + aX1) + (aX2 + aX3);
    float o1 = (aY0 + aY1) + (aY2 + aY3);
    o0 = fmaf(o0, inv, b2.x);
    o1 = fmaf(o1, inv, b2.y);
    o0 = o0 > 0.f ? o0 : 0.01f * o0;
    o1 = o1 > 0.f ? o1 : 0.01f * o1;
    float2 o2 = {o0, o1};
    ((float2*)(y + (size_t)i * 128))[lane] = o2;
    s0 += o0; s1 += o1;
    q0 = fmaf(o0, o0, q0); q1 = fmaf(o1, o1, q1);
  }
  __shared__ float red[4][4][64];
  red[0][w][lane] = s0; red[1][w][lane] = s1; red[2][w][lane] = q0; red[3][w][lane] = q1;
  __syncthreads();
  if (w == 0) {
    for (int ww = 1; ww < 4; ++ww) {
      s0 += red[0][ww][lane]; s1 += red[1][ww][lane];
      q0 += red[2][ww][lane]; q1 += red[3][ww][lane];
    }
    atomicAdd(&colsum[2 * lane], s0);
    atomicAdd(&colsum[2 * lane + 1], s1);
    atomicAdd(&colsumsq[2 * lane], q0);
    atomicAdd(&colsumsq[2 * lane + 1], q1);
  }
}

// final BN: compute scale/shift from colstats in-block, then apply y -> out
__global__ __launch_bounds__(256) void k_bnapply_final(
    const float4* __restrict__ yin, const float* __restrict__ colstats,
    const float* __restrict__ g, const float* __restrict__ be, float invN,
    float4* __restrict__ yout, int total4) {
  __shared__ float sc_s[128], sh_s[128];
  int t = threadIdx.x;
  if (t < 128) {
    float mu = colstats[t] * invN;
    float var = colstats[128 + t] * invN - mu * mu;
    var = var > 0.f ? var : 0.f;
    float sc = g[t] * rsqrtf(var + 1e-5f);
    sc_s[t] = sc;
    sh_s[t] = be[t] - mu * sc;
  }
  __syncthreads();
  for (int i = blockIdx.x * blockDim.x + t; i < total4; i += gridDim.x * blockDim.x) {
    int c4 = (i & 31) << 2;
    float4 v = yin[i];
    v.x = fmaf(v.x, sc_s[c4 + 0], sh_s[c4 + 0]);
    v.y = fmaf(v.y, sc_s[c4 + 1], sh_s[c4 + 1]);
    v.z = fmaf(v.z, sc_s[c4 + 2], sh_s[c4 + 2]);
    v.w = fmaf(v.w, sc_s[c4 + 3], sh_s[c4 + 3]);
    yout[i] = v;
  }
}

extern "C" void kernel_launch(void* const* d_in, const int* in_sizes, int n_in,
                              void* d_out, int out_size, void* d_ws, size_t ws_size,
                              hipStream_t stream) {
  const float* x = (const float*)d_in[0];
  const int* eidx = (const int*)d_in[1];
  const float* ea = (const float*)d_in[3];
  const int H = 128;
  const int N = in_sizes[0] / H;
  const int E = in_sizes[1] / 2;
  const int* srcIdx = eidx;
  const int* dstIdx = eidx + E;

  char* ws = (char*)d_ws;
  size_t off = 0;
  auto alloc = [&](size_t bytes) -> void* {
    void* p = ws + off;
    off = (off + bytes + 255) & ~(size_t)255;
    return p;
  };
  Edge* edges = (Edge*)alloc((size_t)E * sizeof(Edge));
  int* srcs = (int*)alloc((size_t)E * sizeof(int));
  int* dsts = (int*)alloc((size_t)E * sizeof(int));
  float* pexp = (float*)alloc((size_t)E * sizeof(float));
  unsigned* hb = (unsigned*)alloc((size_t)N * 64 * sizeof(unsigned));  // bf16 h
  float* y = (float*)alloc((size_t)N * H * sizeof(float));
  float* al_s = (float*)alloc((size_t)N * sizeof(float));
  float* al_d = (float*)alloc((size_t)N * sizeof(float));
  float* es = (float*)alloc((size_t)N * sizeof(float));
  // deg8 replicas and ea_sum in one region -> one memset
  int* deg8 = (int*)alloc(((size_t)NREP * N + 64) * sizeof(int));
  float* ea_sum = (float*)(deg8 + (size_t)NREP * N);
  int* cursor8 = (int*)alloc((size_t)NREP * N * sizeof(int));
  int* start = (int*)alloc((size_t)(N + 1) * sizeof(int));
  int* bsum = (int*)alloc(64 * sizeof(int));
  float* colstats = (float*)alloc(256 * sizeof(float));
  float* colsum = colstats;
  float* colsumsq = colstats + 128;
  float* scale = (float*)alloc(128 * sizeof(float));
  float* shift = (float*)alloc(128 * sizeof(float));
  float* P = (float*)alloc(16 * sizeof(float));

  const int nb = (N + 1023) / 1024;  // <= 64
  const float invE = 1.0f / (float)E;
  const float invN = 1.0f / (float)N;

  // ---- setup: sort edges by destination (CSR), XCD-local atomics ----
  hipMemsetAsync(deg8, 0, ((size_t)NREP * N + 64) * sizeof(int), stream);
  k_hist_ea8<<<1024, 256, 0, stream>>>(dstIdx, ea, E, deg8, N, ea_sum);
  k_scan_a<<<nb, 1024, 0, stream>>>(deg8, N, start, bsum);
  k_scan_b<<<1, 64, 0, stream>>>(bsum, nb, start, N);
  k_scan_c<<<(N + 255) / 256, 256, 0, stream>>>(start, bsum, deg8, N, cursor8);
  k_scatter8<<<1024, 256, 0, stream>>>(srcIdx, dstIdx, ea, E, N, cursor8, edges, srcs, dsts);

  // layer parameter pointers
  const float* Wl[3]; const float* asl[3]; const float* adl[3]; const float* Wel[3];
  const float* ael[3]; const float* bl[3]; const float* gl[3]; const float* bel[3];
  for (int l = 0; l < 3; ++l) {
    Wl[l] = (const float*)d_in[4 + 8 * l + 0];
    asl[l] = (const float*)d_in[4 + 8 * l + 1];
    adl[l] = (const float*)d_in[4 + 8 * l + 2];
    Wel[l] = (const float*)d_in[4 + 8 * l + 3];
    ael[l] = (const float*)d_in[4 + 8 * l + 4];
    bl[l] = (const float*)d_in[4 + 8 * l + 5];
    gl[l] = (const float*)d_in[4 + 8 * l + 6];
    bel[l] = (const float*)d_in[4 + 8 * l + 7];
  }

  k_param0<<<1, 192, 0, stream>>>(Wel[0], ael[0], ea_sum, invE, P, scale, shift, colstats);

  const float* X = x;
  for (int l = 0; l < 3; ++l) {
    k_gemm2<<<512, 256, 0, stream>>>(X, Wl[l], scale, shift, asl[l], adl[l], P,
                                     hb, al_s, al_d, es, N);
    k_alpha2<<<(E + 255) / 256, 256, 0, stream>>>((const float4*)edges, dsts, al_s, al_d, P,
                                                  pexp, E);
    k_agg4<<<2048, 256, 0, stream>>>(srcs, pexp, start, hb, es, bl[l], y,
                                     colsum, colsumsq, N);
    if (l < 2) {
      k_inter<<<1, 192, 0, stream>>>(colstats, gl[l], bel[l], invN, scale, shift,
                                     Wel[l + 1], ael[l + 1], ea_sum, invE, P, colstats);
    }
    X = y;
  }
  k_bnapply_final<<<384, 256, 0, stream>>>((const float4*)y, colstats, gl[2], bel[2], invN,
                                           (float4*)d_out, N * 32);
}

// Round 9
// 761.954 us; speedup vs baseline: 2.1604x; 1.1665x over previous
//
#include <hip/hip_runtime.h>
#include <hip/hip_fp16.h>
#include <math.h>

// ---------------------------------------------------------------------------
// GAT x3 + BN on MI355X.
//   setup (NO global atomics — R8 showed each device-scope atomic is an
//   uncached 32B-sector RMW at memory: 800k atomics = ~180us):
//     k_hist_lds:  64 blocks, private LDS histogram (packed u16, 100KB dyn
//                  LDS) + ea col sums; plane dumped coalesced.
//     k_scan_a/b/c: sum 64 planes -> exclusive scan -> per-(block,node)
//                  cursor bases.
//     k_scatter_lds: same edge partition; rank via LDS packed-u16 atomic;
//                  pos = cursorp[b][d]+rank; writes ONE 16B struct
//                  {src,dst,3xfp16 ea} per edge.
//   layer:  k_gemm2: h = BN(X)@W (W in LDS, 4x4 reg tile) -> bf16 h,
//                    fused al_s/al_d/es epilogue
//           k_alpha2b: pexp[e] = exp(lrelu(als[src]+ald[dst]+ea.P))
//           k_agg4: one wave/node, wave-uniform scalar meta loads, 8-deep
//                   unrolled bf16 row gathers, 4 acc pairs, + bias+lrelu+BN
//                   [R4 shape = measured optimum; R5/R6 variants regressed]
//           k_inter: BN finalize + zero stats + next layer's param (1 block)
//           k_bnapply_final: scale/shift in-block, apply -> out
// ---------------------------------------------------------------------------

#define NB 64  // blocks for hist/scatter (same partition in both)

struct __align__(16) Edge2 { int src; int dst; unsigned e01; unsigned e2; };

__device__ __forceinline__ unsigned short f2bf(float x) {
  unsigned u = __float_as_uint(x);
  unsigned r = (u + 0x7FFFu + ((u >> 16) & 1u)) >> 16;  // RNE
  return (unsigned short)r;
}
__device__ __forceinline__ float bf_lo(unsigned u) { return __uint_as_float(u << 16); }
__device__ __forceinline__ float bf_hi(unsigned u) { return __uint_as_float(u & 0xFFFF0000u); }

// 64 blocks; private LDS histogram (packed u16) + ea column sums
__global__ void k_hist_lds(const int* __restrict__ dst, const float* __restrict__ ea, int E,
                           int n, unsigned* __restrict__ hist32, float* __restrict__ ea_sum) {
  extern __shared__ unsigned cnt[];
  int nh = (n + 1) >> 1;
  for (int i = threadIdx.x; i < nh; i += blockDim.x) cnt[i] = 0u;
  __syncthreads();
  int tid = blockIdx.x * blockDim.x + threadIdx.x;
  int stride = gridDim.x * blockDim.x;
  float s0 = 0.f, s1 = 0.f, s2 = 0.f;
  for (int i = tid; i < E; i += stride) {
    int d = dst[i];
    atomicAdd(&cnt[d >> 1], 1u << ((d & 1) << 4));
    s0 += ea[i * 3 + 0]; s1 += ea[i * 3 + 1]; s2 += ea[i * 3 + 2];
  }
  for (int off = 32; off; off >>= 1) {
    s0 += __shfl_down(s0, off); s1 += __shfl_down(s1, off); s2 += __shfl_down(s2, off);
  }
  if ((threadIdx.x & 63) == 0) {
    atomicAdd(&ea_sum[0], s0); atomicAdd(&ea_sum[1], s1); atomicAdd(&ea_sum[2], s2);
  }
  __syncthreads();
  unsigned* plane = hist32 + (size_t)blockIdx.x * nh;
  for (int i = threadIdx.x; i < nh; i += blockDim.x) plane[i] = cnt[i];
}

__device__ __forceinline__ int wave_incl_scan(int x, int lane) {
  for (int off = 1; off < 64; off <<= 1) {
    int t = __shfl_up(x, off);
    if (lane >= off) x += t;
  }
  return x;
}

// phase A: sum NB planes -> per-block exclusive scan -> start[], block sums
__global__ __launch_bounds__(1024) void k_scan_a(const unsigned* __restrict__ hist32, int n,
                                                 int* __restrict__ start,
                                                 int* __restrict__ bsum) {
  __shared__ int wsum[16];
  int t = threadIdx.x, lane = t & 63, w = t >> 6;
  int i = blockIdx.x * 1024 + t;
  int nh = (n + 1) >> 1;
  int stride2 = nh * 2;
  const unsigned short* h16 = (const unsigned short*)hist32;
  int v = 0;
  if (i < n) {
    for (int r = 0; r < NB; ++r) v += h16[(size_t)r * stride2 + i];
  }
  int x = wave_incl_scan(v, lane);
  if (lane == 63) wsum[w] = x;
  __syncthreads();
  if (w == 0 && lane < 16) {
    int s = wsum[lane];
    for (int off = 1; off < 16; off <<= 1) {
      int u = __shfl_up(s, off);
      if (lane >= off) s += u;
    }
    wsum[lane] = s;
  }
  __syncthreads();
  int woff = w ? wsum[w - 1] : 0;
  if (i < n) start[i] = x - v + woff;
  if (t == 1023) bsum[blockIdx.x] = wsum[15];
}

__global__ void k_scan_b(int* __restrict__ bsum, int nb, int* __restrict__ start, int n) {
  int lane = threadIdx.x;  // 64
  int v = (lane < nb) ? bsum[lane] : 0;
  int x = wave_incl_scan(v, lane);
  if (lane < nb) bsum[lane] = x - v;
  if (lane == nb - 1) start[n] = x;
}

// phase C: finalize start; emit per-(block,node) cursor bases
__global__ void k_scan_c(int* __restrict__ start, const int* __restrict__ bsum,
                         const unsigned* __restrict__ hist32, int n,
                         int* __restrict__ cursorp) {
  int i = blockIdx.x * blockDim.x + threadIdx.x;
  if (i >= n) return;
  int nh = (n + 1) >> 1;
  int stride2 = nh * 2;
  const unsigned short* h16 = (const unsigned short*)hist32;
  int s = start[i] + bsum[i >> 10];
  start[i] = s;
  int run = s;
  for (int r = 0; r < NB; ++r) {
    cursorp[(size_t)r * n + i] = run;
    run += h16[(size_t)r * stride2 + i];
  }
}

// same 64-block edge partition as hist; rank via LDS packed-u16 atomic;
// writes one 16B struct per edge — NO global atomics.
__global__ void k_scatter_lds(const int* __restrict__ src, const int* __restrict__ dst,
                              const float* __restrict__ ea, int E, int n,
                              const int* __restrict__ cursorp, Edge2* __restrict__ edges) {
  extern __shared__ unsigned cnt[];
  int nh = (n + 1) >> 1;
  for (int i = threadIdx.x; i < nh; i += blockDim.x) cnt[i] = 0u;
  __syncthreads();
  const int* cur = cursorp + (size_t)blockIdx.x * n;
  int tid = blockIdx.x * blockDim.x + threadIdx.x;
  int stride = gridDim.x * blockDim.x;
  for (int i = tid; i < E; i += stride) {
    int d = dst[i];
    int sh = (d & 1) << 4;
    unsigned old = atomicAdd(&cnt[d >> 1], 1u << sh);
    int rank = (old >> sh) & 0xFFFF;
    int pos = cur[d] + rank;
    unsigned short h0 = __half_as_ushort(__float2half(ea[i * 3 + 0]));
    unsigned short h1 = __half_as_ushort(__float2half(ea[i * 3 + 1]));
    unsigned short h2 = __half_as_ushort(__float2half(ea[i * 3 + 2]));
    Edge2 e;
    e.src = src[i];
    e.dst = d;
    e.e01 = (unsigned)h0 | ((unsigned)h1 << 16);
    e.e2 = (unsigned)h2;
    edges[pos] = e;
  }
}

__device__ __forceinline__ void param_wave(const float* __restrict__ We,
                                           const float* __restrict__ ae,
                                           const float* __restrict__ ea_sum, float invE,
                                           float* __restrict__ P, int lane) {
  float a0 = ae[lane], a1 = ae[64 + lane];
  float p0 = We[0 * 128 + lane] * a0 + We[0 * 128 + 64 + lane] * a1;
  float p1 = We[1 * 128 + lane] * a0 + We[1 * 128 + 64 + lane] * a1;
  float p2 = We[2 * 128 + lane] * a0 + We[2 * 128 + 64 + lane] * a1;
  for (int off = 32; off; off >>= 1) {
    p0 += __shfl_down(p0, off); p1 += __shfl_down(p1, off); p2 += __shfl_down(p2, off);
  }
  if (lane == 0) {
    P[0] = p0; P[1] = p1; P[2] = p2;
    P[3] = ea_sum[0] * invE * p0 + ea_sum[1] * invE * p1 + ea_sum[2] * invE * p2;
  }
}

__global__ void k_param0(const float* __restrict__ We, const float* __restrict__ ae,
                         const float* __restrict__ ea_sum, float invE, float* __restrict__ P,
                         float* __restrict__ scale, float* __restrict__ shift,
                         float* __restrict__ colstats) {
  int t = threadIdx.x;
  if (t < 64) {
    param_wave(We, ae, ea_sum, invE, P, t);
  } else if (t < 192) {
    int c = t - 64;
    scale[c] = 1.f; shift[c] = 0.f;
    colstats[c] = 0.f; colstats[128 + c] = 0.f;
  }
}

__global__ void k_inter(const float* __restrict__ colstatsIn, const float* __restrict__ g,
                        const float* __restrict__ be, float invN,
                        float* __restrict__ scale, float* __restrict__ shift,
                        const float* __restrict__ WeN, const float* __restrict__ aeN,
                        const float* __restrict__ ea_sum, float invE, float* __restrict__ P,
                        float* __restrict__ colstats) {
  int t = threadIdx.x;
  if (t < 64) {
    param_wave(WeN, aeN, ea_sum, invE, P, t);
  } else if (t < 192) {
    int c = t - 64;
    float mu = colstatsIn[c] * invN;
    float var = colstatsIn[128 + c] * invN - mu * mu;
    var = var > 0.f ? var : 0.f;
    float sc = g[c] * rsqrtf(var + 1e-5f);
    scale[c] = sc;
    shift[c] = be[c] - mu * sc;
    colstats[c] = 0.f; colstats[128 + c] = 0.f;
  }
}

// h[N,128] = (X*bnsc+bnsh) @ W, stored as bf16 rows (256 B).  W in LDS,
// 32-row tiles, 4 rows x 4 cols per thread.  Fused al_s/al_d/es epilogue.
__global__ __launch_bounds__(256) void k_gemm2(
    const float* __restrict__ X, const float* __restrict__ Wm,
    const float* __restrict__ bnsc, const float* __restrict__ bnsh,
    const float* __restrict__ as, const float* __restrict__ ad,
    const float* __restrict__ P,
    unsigned* __restrict__ hb, float* __restrict__ al_s, float* __restrict__ al_d,
    float* __restrict__ es, int n) {
  __shared__ float wl[128 * 128];
  __shared__ float xs[32 * 128];
  int t = threadIdx.x;
  for (int i = t; i < 4096; i += 256) ((float4*)wl)[i] = ((const float4*)Wm)[i];
  int c32 = t & 31;
  int c4 = c32 << 2;
  int rq = t >> 5;
  int lane = t & 63;
  float4 av_s = *(const float4*)(as + c4);
  float4 av_d = *(const float4*)(ad + c4);
  float cself = P[3];
  int ntiles = (n + 31) >> 5;
  for (int tile = blockIdx.x; tile < ntiles; tile += gridDim.x) {
    int r0 = tile << 5;
    __syncthreads();
    for (int i = t; i < 1024; i += 256) {
      int rr = i >> 5, cc = i & 31;
      int g = r0 + rr;
      float4 v;
      if (g < n) {
        v = ((const float4*)(X + (size_t)g * 128))[cc];
        float4 sc = ((const float4*)bnsc)[cc];
        float4 sh = ((const float4*)bnsh)[cc];
        v.x = fmaf(v.x, sc.x, sh.x); v.y = fmaf(v.y, sc.y, sh.y);
        v.z = fmaf(v.z, sc.z, sh.z); v.w = fmaf(v.w, sc.w, sh.w);
      } else { v.x = v.y = v.z = v.w = 0.f; }
      ((float4*)xs)[i] = v;
    }
    __syncthreads();
    float4 acc[4];
    for (int r = 0; r < 4; ++r) { acc[r].x = acc[r].y = acc[r].z = acc[r].w = 0.f; }
    const float* xr = xs + (rq << 2) * 128;
#pragma unroll 4
    for (int k = 0; k < 128; ++k) {
      float4 w4 = ((const float4*)wl)[(k << 5) + c32];
#pragma unroll
      for (int r = 0; r < 4; ++r) {
        float xv = xr[r * 128 + k];
        acc[r].x = fmaf(xv, w4.x, acc[r].x);
        acc[r].y = fmaf(xv, w4.y, acc[r].y);
        acc[r].z = fmaf(xv, w4.z, acc[r].z);
        acc[r].w = fmaf(xv, w4.w, acc[r].w);
      }
    }
    int gbase = r0 + (rq << 2);
#pragma unroll
    for (int r = 0; r < 4; ++r) {
      int g = gbase + r;
      float4 o = acc[r];
      if (g < n) {
        unsigned u01 = ((unsigned)f2bf(o.y) << 16) | (unsigned)f2bf(o.x);
        unsigned u23 = ((unsigned)f2bf(o.w) << 16) | (unsigned)f2bf(o.z);
        uint2 uu = {u01, u23};
        *(uint2*)(hb + (size_t)g * 64 + (c32 << 1)) = uu;
      }
      float ps = o.x * av_s.x + o.y * av_s.y + o.z * av_s.z + o.w * av_s.w;
      float pd = o.x * av_d.x + o.y * av_d.y + o.z * av_d.z + o.w * av_d.w;
      for (int off = 16; off; off >>= 1) {
        ps += __shfl_xor(ps, off);
        pd += __shfl_xor(pd, off);
      }
      if ((lane & 31) == 0 && g < n) {
        al_s[g] = ps; al_d[g] = pd;
        float a = ps + pd + cself;
        a = a > 0.f ? a : 0.2f * a;
        es[g] = __expf(a);
      }
    }
  }
}

// flat per-edge: pexp[e] = exp(lrelu_0.2(al_s[src] + al_d[dst] + ea.P))
__global__ __launch_bounds__(256) void k_alpha2b(const int4* __restrict__ edges,
                                                 const float* __restrict__ al_s,
                                                 const float* __restrict__ al_d,
                                                 const float* __restrict__ P,
                                                 float* __restrict__ pexp, int E) {
  int i = blockIdx.x * blockDim.x + threadIdx.x;
  if (i >= E) return;
  int4 ev = edges[i];
  float e0 = __half2float(__ushort_as_half((unsigned short)(ev.z & 0xFFFF)));
  float e1 = __half2float(__ushort_as_half((unsigned short)(((unsigned)ev.z) >> 16)));
  float e2 = __half2float(__ushort_as_half((unsigned short)(ev.w & 0xFFFF)));
  float a = al_s[ev.x] + al_d[ev.y] + e0 * P[0] + e1 * P[1] + e2 * P[2];
  a = a > 0.f ? a : 0.2f * a;
  pexp[i] = __expf(a);
}

// one wave per node.  Edge meta (src from 16B struct, pexp) via wave-uniform
// scalar loads; bf16 row gathers (4 B/lane), 8-deep unroll, 4 acc pairs.
__global__ __launch_bounds__(256) void k_agg4(const Edge2* __restrict__ edges,
                                              const float* __restrict__ pexp,
                                              const int* __restrict__ start,
                                              const unsigned* __restrict__ hb,
                                              const float* __restrict__ es,
                                              const float* __restrict__ bias,
                                              float* __restrict__ y,
                                              float* __restrict__ colsum,
                                              float* __restrict__ colsumsq, int n) {
  int lane = threadIdx.x & 63;
  int w = threadIdx.x >> 6;
  int gw = (blockIdx.x * blockDim.x + threadIdx.x) >> 6;
  int nw = (gridDim.x * blockDim.x) >> 6;
  float2 b2 = ((const float2*)bias)[lane];
  float s0 = 0.f, s1 = 0.f, q0 = 0.f, q1 = 0.f;
  for (int i = gw; i < n; i += nw) {
    int e0 = __builtin_amdgcn_readfirstlane(start[i]);
    int e1 = __builtin_amdgcn_readfirstlane(start[i + 1]);
    float eself = es[i];
    unsigned hv = hb[(size_t)i * 64 + lane];
    float aX0 = eself * bf_lo(hv), aY0 = eself * bf_hi(hv);
    float aX1 = 0.f, aY1 = 0.f, aX2 = 0.f, aY2 = 0.f, aX3 = 0.f, aY3 = 0.f;
    float pacc = 0.f;
    int e = e0;
    for (; e + 8 <= e1; e += 8) {
      int sv[8]; float pv[8]; unsigned gv[8];
#pragma unroll
      for (int k = 0; k < 8; ++k) sv[k] = edges[e + k].src;
#pragma unroll
      for (int k = 0; k < 8; ++k) pv[k] = pexp[e + k];
#pragma unroll
      for (int k = 0; k < 8; ++k) gv[k] = hb[(size_t)sv[k] * 64 + lane];
#pragma unroll
      for (int k = 0; k < 8; ++k) {
        float gx = bf_lo(gv[k]);
        float gy = bf_hi(gv[k]);
        pacc += pv[k];
        if ((k & 3) == 0) { aX0 = fmaf(pv[k], gx, aX0); aY0 = fmaf(pv[k], gy, aY0); }
        else if ((k & 3) == 1) { aX1 = fmaf(pv[k], gx, aX1); aY1 = fmaf(pv[k], gy, aY1); }
        else if ((k & 3) == 2) { aX2 = fmaf(pv[k], gx, aX2); aY2 = fmaf(pv[k], gy, aY2); }
        else { aX3 = fmaf(pv[k], gx, aX3); aY3 = fmaf(pv[k], gy, aY3); }
      }
    }
    for (; e < e1; ++e) {
      int sv = edges[e].src;
      float pv = pexp[e];
      unsigned gv = hb[(size_t)sv * 64 + lane];
      pacc += pv;
      aX0 = fmaf(pv, bf_lo(gv), aX0); aY0 = fmaf(pv, bf_hi(gv), aY0);
    }
    float inv = 1.0f / (eself + pacc + 1e-16f);
    float o0 = (aX0 + aX1) + (aX2 + aX3);
    float o1 = (aY0 + aY1) + (aY2 + aY3);
    o0 = fmaf(o0, inv, b2.x);
    o1 = fmaf(o1, inv, b2.y);
    o0 = o0 > 0.f ? o0 : 0.01f * o0;
    o1 = o1 > 0.f ? o1 : 0.01f * o1;
    float2 o2 = {o0, o1};
    ((float2*)(y + (size_t)i * 128))[lane] = o2;
    s0 += o0; s1 += o1;
    q0 = fmaf(o0, o0, q0); q1 = fmaf(o1, o1, q1);
  }
  __shared__ float red[4][4][64];
  red[0][w][lane] = s0; red[1][w][lane] = s1; red[2][w][lane] = q0; red[3][w][lane] = q1;
  __syncthreads();
  if (w == 0) {
    for (int ww = 1; ww < 4; ++ww) {
      s0 += red[0][ww][lane]; s1 += red[1][ww][lane];
      q0 += red[2][ww][lane]; q1 += red[3][ww][lane];
    }
    atomicAdd(&colsum[2 * lane], s0);
    atomicAdd(&colsum[2 * lane + 1], s1);
    atomicAdd(&colsumsq[2 * lane], q0);
    atomicAdd(&colsumsq[2 * lane + 1], q1);
  }
}

// final BN: compute scale/shift from colstats in-block, then apply y -> out
__global__ __launch_bounds__(256) void k_bnapply_final(
    const float4* __restrict__ yin, const float* __restrict__ colstats,
    const float* __restrict__ g, const float* __restrict__ be, float invN,
    float4* __restrict__ yout, int total4) {
  __shared__ float sc_s[128], sh_s[128];
  int t = threadIdx.x;
  if (t < 128) {
    float mu = colstats[t] * invN;
    float var = colstats[128 + t] * invN - mu * mu;
    var = var > 0.f ? var : 0.f;
    float sc = g[t] * rsqrtf(var + 1e-5f);
    sc_s[t] = sc;
    sh_s[t] = be[t] - mu * sc;
  }
  __syncthreads();
  for (int i = blockIdx.x * blockDim.x + t; i < total4; i += gridDim.x * blockDim.x) {
    int c4 = (i & 31) << 2;
    float4 v = yin[i];
    v.x = fmaf(v.x, sc_s[c4 + 0], sh_s[c4 + 0]);
    v.y = fmaf(v.y, sc_s[c4 + 1], sh_s[c4 + 1]);
    v.z = fmaf(v.z, sc_s[c4 + 2], sh_s[c4 + 2]);
    v.w = fmaf(v.w, sc_s[c4 + 3], sh_s[c4 + 3]);
    yout[i] = v;
  }
}

extern "C" void kernel_launch(void* const* d_in, const int* in_sizes, int n_in,
                              void* d_out, int out_size, void* d_ws, size_t ws_size,
                              hipStream_t stream) {
  const float* x = (const float*)d_in[0];
  const int* eidx = (const int*)d_in[1];
  const float* ea = (const float*)d_in[3];
  const int H = 128;
  const int N = in_sizes[0] / H;
  const int E = in_sizes[1] / 2;
  const int* srcIdx = eidx;
  const int* dstIdx = eidx + E;
  const int nh = (N + 1) >> 1;

  char* ws = (char*)d_ws;
  size_t off = 0;
  auto alloc = [&](size_t bytes) -> void* {
    void* p = ws + off;
    off = (off + bytes + 255) & ~(size_t)255;
    return p;
  };
  Edge2* edges = (Edge2*)alloc((size_t)E * sizeof(Edge2));
  float* pexp = (float*)alloc((size_t)E * sizeof(float));
  unsigned* hb = (unsigned*)alloc((size_t)N * 64 * sizeof(unsigned));  // bf16 h
  float* y = (float*)alloc((size_t)N * H * sizeof(float));
  float* al_s = (float*)alloc((size_t)N * sizeof(float));
  float* al_d = (float*)alloc((size_t)N * sizeof(float));
  float* es = (float*)alloc((size_t)N * sizeof(float));
  unsigned* hist32 = (unsigned*)alloc((size_t)NB * nh * sizeof(unsigned));
  int* cursorp = (int*)alloc((size_t)NB * N * sizeof(int));
  int* start = (int*)alloc((size_t)(N + 1) * sizeof(int));
  int* bsum = (int*)alloc(64 * sizeof(int));
  float* colstats = (float*)alloc(256 * sizeof(float));
  float* colsum = colstats;
  float* colsumsq = colstats + 128;
  float* scale = (float*)alloc(128 * sizeof(float));
  float* shift = (float*)alloc(128 * sizeof(float));
  float* ea_sum = (float*)alloc(64 * sizeof(float));
  float* P = (float*)alloc(16 * sizeof(float));

  const int nb = (N + 1023) / 1024;  // <= 64
  const float invE = 1.0f / (float)E;
  const float invN = 1.0f / (float)N;
  const size_t ldsBytes = (size_t)nh * sizeof(unsigned);  // 100 KB @ N=50k

  // ---- setup: CSR sort with LDS-only atomics ----
  hipMemsetAsync(ea_sum, 0, 64 * sizeof(float), stream);
  k_hist_lds<<<NB, 256, ldsBytes, stream>>>(dstIdx, ea, E, N, hist32, ea_sum);
  k_scan_a<<<nb, 1024, 0, stream>>>(hist32, N, start, bsum);
  k_scan_b<<<1, 64, 0, stream>>>(bsum, nb, start, N);
  k_scan_c<<<(N + 255) / 256, 256, 0, stream>>>(start, bsum, hist32, N, cursorp);
  k_scatter_lds<<<NB, 256, ldsBytes, stream>>>(srcIdx, dstIdx, ea, E, N, cursorp, edges);

  // layer parameter pointers
  const float* Wl[3]; const float* asl[3]; const float* adl[3]; const float* Wel[3];
  const float* ael[3]; const float* bl[3]; const float* gl[3]; const float* bel[3];
  for (int l = 0; l < 3; ++l) {
    Wl[l] = (const float*)d_in[4 + 8 * l + 0];
    asl[l] = (const float*)d_in[4 + 8 * l + 1];
    adl[l] = (const float*)d_in[4 + 8 * l + 2];
    Wel[l] = (const float*)d_in[4 + 8 * l + 3];
    ael[l] = (const float*)d_in[4 + 8 * l + 4];
    bl[l] = (const float*)d_in[4 + 8 * l + 5];
    gl[l] = (const float*)d_in[4 + 8 * l + 6];
    bel[l] = (const float*)d_in[4 + 8 * l + 7];
  }

  k_param0<<<1, 192, 0, stream>>>(Wel[0], ael[0], ea_sum, invE, P, scale, shift, colstats);

  const float* X = x;
  for (int l = 0; l < 3; ++l) {
    k_gemm2<<<512, 256, 0, stream>>>(X, Wl[l], scale, shift, asl[l], adl[l], P,
                                     hb, al_s, al_d, es, N);
    k_alpha2b<<<(E + 255) / 256, 256, 0, stream>>>((const int4*)edges, al_s, al_d, P,
                                                   pexp, E);
    k_agg4<<<2048, 256, 0, stream>>>(edges, pexp, start, hb, es, bl[l], y,
                                     colsum, colsumsq, N);
    if (l < 2) {
      k_inter<<<1, 192, 0, stream>>>(colstats, gl[l], bel[l], invN, scale, shift,
                                     Wel[l + 1], ael[l + 1], ea_sum, invE, P, colstats);
    }
    X = y;
  }
  k_bnapply_final<<<384, 256, 0, stream>>>((const float4*)y, colstats, gl[2], bel[2], invN,
                                           (float4*)d_out, N * 32);
}